// Round 8
// baseline (648.798 us; speedup 1.0000x reference)
//
#include <hip/hip_runtime.h>
#include <hip/hip_fp16.h>

// ---------------------------------------------------------------------------
// VQFFN1: out = softmax(rmsnorm(x) @ rmsnorm(w)^T) @ w
//   x: [16384,1024] fp32   w: [4096,1024] fp32   out: [16384,1024] fp32
// fp32 scores; GEMM2 plain fp16 + split-K + f32 HW atomics.
// R2: XOR-swizzled LDS (bank conflicts 3.8e7 -> 0).
// R8: gemm2 BK 64->128: 650us; gemm1 at MfmaUtil 43%.
// R9/R10/R11 FAILED: fine-phase / 1-block-per-CU schedules lost the
//     2-blocks/CU implicit overlap (m114); 26-40% MfmaUtil. Lane closed.
// R12 NEUTRAL: 32x32x16: inherent 4-way LDS conflict at BK=64. Lane closed.
// R13 WIN (-80us): dropped xl@wh -> single-pass fp16 gemm1 (absmax 9.2e-4,
//     passes; P->fp16 quantization dominates). 570us. gemm2 now frontier:
//     58us at MfmaUtil 21%, 4.19e6 bank-conflict cycles (BK=128 slot-alias:
//     slot s and s+8 share banks; 4 cyc per b128 read).
// R14: gemm2 reshaped to gemm1's exact economics: 256x128 tile, BK=64,
//     wave tile 128x64 (acc[8][4], 12 reads -> 32 MFMA per ks, the
//     measured-0-conflict pattern), 48KB LDS -> 2 blocks/CU, split-K=4
//     (grid 8x16x4 = 512 = 2/CU). Atomic passes 2->4 (~+5us, R7-measured).
// ---------------------------------------------------------------------------

#define D_MODEL 1024
#define D_FF    4096
#define M_ROWS  16384
#define MC      4096

typedef _Float16 half8 __attribute__((ext_vector_type(8)));
typedef _Float16 half4 __attribute__((ext_vector_type(4)));
typedef float    floatx4 __attribute__((ext_vector_type(4)));

// async global->LDS, 16B/lane; LDS dst = wave-uniform base + lane*16 (m97)
__device__ __forceinline__ void gld_lds16(const void* g, void* l) {
  __builtin_amdgcn_global_load_lds(
      (const __attribute__((address_space(1))) void*)g,
      (__attribute__((address_space(3))) void*)l, 16, 0, 0);
}

// ---------------------------------------------------------------------------
// rmsnorm (fp32 in) -> fp16. One wave per row of 1024.
// ---------------------------------------------------------------------------
#define MB_X (M_ROWS / 4)
#define MB_W (D_FF / 4)
__global__ __launch_bounds__(256) void rmsnorm_kernel(
    const float* __restrict__ X, _Float16* __restrict__ XH,
    const float* __restrict__ W, _Float16* __restrict__ WH) {
  const int lane = threadIdx.x & 63;
  const bool isW = blockIdx.x >= MB_X;
  const long row = (long)(isW ? blockIdx.x - MB_X : blockIdx.x) * 4 +
                   (threadIdx.x >> 6);
  const float* x = (isW ? W : X) + row * D_MODEL;
  _Float16* YH = (isW ? WH : XH) + row * D_MODEL;

  float v[16];
  float ss = 0.f;
#pragma unroll
  for (int s = 0; s < 4; s++) {
    const float4 f = *(const float4*)(x + s * 256 + lane * 4);
    v[s * 4 + 0] = f.x; v[s * 4 + 1] = f.y;
    v[s * 4 + 2] = f.z; v[s * 4 + 3] = f.w;
    ss += f.x * f.x + f.y * f.y + f.z * f.z + f.w * f.w;
  }
#pragma unroll
  for (int off = 32; off >= 1; off >>= 1) ss += __shfl_xor(ss, off);
  const float inv = rsqrtf(ss * (1.0f / D_MODEL) + 1e-6f);
#pragma unroll
  for (int s = 0; s < 4; s++) {
    half4 h;
#pragma unroll
    for (int j = 0; j < 4; j++) h[j] = (_Float16)(v[s * 4 + j] * inv);
    *(half4*)(YH + s * 256 + lane * 4) = h;
  }
}

// ---------------------------------------------------------------------------
// transpose w [4096,1024] fp32 -> wT [1024,4096] fp16 (unnormalized, GEMM2 B)
// ---------------------------------------------------------------------------
__global__ __launch_bounds__(256) void transpose_kernel(
    const float* __restrict__ W, _Float16* __restrict__ WT) {
  __shared__ _Float16 tile[32][33];
  const int tx = threadIdx.x & 31;
  const int ty = threadIdx.x >> 5;  // 0..7
  const int d0 = blockIdx.x * 32;
  const int c0 = blockIdx.y * 32;
#pragma unroll
  for (int i = 0; i < 32; i += 8)
    tile[ty + i][tx] = (_Float16)W[(long)(c0 + ty + i) * D_MODEL + d0 + tx];
  __syncthreads();
#pragma unroll
  for (int i = 0; i < 32; i += 8)
    WT[(long)(d0 + ty + i) * D_FF + c0 + tx] = tile[tx][ty + i];
}

// ---------------------------------------------------------------------------
// GEMM K-loops: m97 structure + R2 XOR swizzle (single LDS buffer).
// LDS slot (row, s) holds global data (row, s ^ (row&7)); swizzle applied by
// permuting the *global source* lane address. Fragment reads XOR the k-slot
// with m16&7 -> conflict-free ds_read_b128 (measured 0).
// ---------------------------------------------------------------------------

// GEMM1: S[4096,4096] fp32 = xh @ wh^T over K=1024.  (single-pass, R13)
// 128x256 block tile, 4 waves, wave tile 64x128 (acc[4][8]); per ks:
// 12 LDS reads feed 32 MFMA. LDS 48KB -> 2 blocks/CU (m114 overlap).
__global__ __launch_bounds__(256, 2) void gemm1_kernel(
    const _Float16* __restrict__ XH, const _Float16* __restrict__ WH,
    float* __restrict__ S) {
  constexpr int BK = 64;
  __shared__ _Float16 Ah[128 * BK];  // xh tile (16 KB)
  __shared__ _Float16 Bs[256 * BK];  // wh tile (32 KB)
  const int tid = threadIdx.x;
  const int wave = tid >> 6, lane = tid & 63;
  const long rowBase = (long)blockIdx.y * 128;
  const long colBase = (long)blockIdx.x * 256;
  const int srow = lane >> 3;
  const int scol = ((lane & 7) ^ (lane >> 3)) * 8;  // XOR-swizzled source col
  const _Float16* AgH = XH + (rowBase + wave * 32 + srow) * (long)D_MODEL + scol;
  const _Float16* Bg  = WH + (colBase + wave * 64 + srow) * (long)D_MODEL + scol;
  const int ldsOffA = wave * 2048 + lane * 8;  // 32 rows/wave
  const int ldsOffB = wave * 4096 + lane * 8;  // 64 rows/wave
  const int wr = wave >> 1, wc = wave & 1;
  const int m16 = lane & 15, q = lane >> 4;
  const int mx7 = m16 & 7;

  floatx4 acc[4][8] = {};

  for (int kt = 0; kt < D_MODEL; kt += BK) {
#pragma unroll
    for (int i = 0; i < 4; i++)
      gld_lds16(AgH + i * 8 * D_MODEL + kt, Ah + ldsOffA + i * 512);
#pragma unroll
    for (int i = 0; i < 8; i++)
      gld_lds16(Bg + i * 8 * D_MODEL + kt, Bs + ldsOffB + i * 512);
    __syncthreads();
#pragma unroll
    for (int ks = 0; ks < 2; ks++) {
      const int kx = ((ks * 4 + q) ^ mx7) * 8;
      half8 b[8], a[4];
#pragma unroll
      for (int ni = 0; ni < 8; ni++)
        b[ni] = *(const half8*)(&Bs[(wc * 128 + ni * 16 + m16) * BK + kx]);
#pragma unroll
      for (int mi = 0; mi < 4; mi++)
        a[mi] = *(const half8*)(&Ah[(wr * 64 + mi * 16 + m16) * BK + kx]);
      __builtin_amdgcn_s_setprio(1);
#pragma unroll
      for (int mi = 0; mi < 4; mi++)
#pragma unroll
        for (int ni = 0; ni < 8; ni++)
          acc[mi][ni] = __builtin_amdgcn_mfma_f32_16x16x32_f16(
              a[mi], b[ni], acc[mi][ni], 0, 0, 0);
      __builtin_amdgcn_s_setprio(0);
    }
    __syncthreads();
  }

  // C/D frag: col = lane&15, row = quad*4 + reg  [m89/m91 verified]
#pragma unroll
  for (int mi = 0; mi < 4; mi++)
#pragma unroll
    for (int r = 0; r < 4; r++) {
      const long rr = rowBase + wr * 64 + mi * 16 + q * 4 + r;
#pragma unroll
      for (int ni = 0; ni < 8; ni++)
        S[rr * D_FF + colBase + wc * 128 + ni * 16 + m16] = acc[mi][ni][r];
    }
}

// ---------------------------------------------------------------------------
// GEMM2: O[4096,1024] fp32 += P[4096, lda 8192] @ WT[1024,4096]^T  (R14)
// 256x128 block tile, BK=64, 4 waves, wave tile 128x64 (acc[8][4]); per ks:
// 12 LDS reads feed 32 MFMA (gemm1 economics, 0-conflict pattern).
// LDS 48KB -> 2 blocks/CU. split-K=4, grid 8x16x4 = 512 = 2/CU.
// HW f32 atomics into pre-zeroed O.
// ---------------------------------------------------------------------------
__global__ __launch_bounds__(256, 2) void gemm2_kernel(
    const _Float16* __restrict__ P, const _Float16* __restrict__ WT,
    float* __restrict__ O) {
  constexpr int BK = 64, K = D_FF, LDA = 2 * D_FF, KSPLIT = 1024;
  __shared__ _Float16 As[256 * BK];  // P tile  (32 KB)
  __shared__ _Float16 Bs[128 * BK];  // wT tile (16 KB)
  const int tid = threadIdx.x;
  const int wave = tid >> 6, lane = tid & 63;

  // XCD-chunked bijective swizzle (nwg = 8*16*4 = 512, %8 == 0)
  const int bid = ((blockIdx.z * 16 + blockIdx.y) << 3) | blockIdx.x;
  const int swz = ((bid & 7) << 6) | (bid >> 3);
  const int bx = swz & 7;          // col-block   0..7   (N/128)
  const int by = (swz >> 3) & 15;  // row-block   0..15  (M/256)
  const int bz = swz >> 7;         // K-split     0..3

  const long rowBase = (long)by * 256;
  const long colBase = (long)bx * 128;
  const int k0 = bz * KSPLIT;

  const int srow = lane >> 3;                       // 0..7
  const int scol = ((lane & 7) ^ (lane >> 3)) * 8;  // XOR-swizzled source col
  const _Float16* Ag = P + (rowBase + wave * 64 + srow) * (long)LDA + scol;
  const _Float16* Bg = WT + (colBase + wave * 32 + srow) * (long)K + scol;
  const int ldsOffA = wave * 4096 + lane * 8;  // 64 rows/wave
  const int ldsOffB = wave * 2048 + lane * 8;  // 32 rows/wave
  const int wr = wave >> 1, wc = wave & 1;
  const int m16 = lane & 15, q = lane >> 4;
  const int mx7 = m16 & 7;

  floatx4 acc[8][4] = {};

  for (int kt = k0; kt < k0 + KSPLIT; kt += BK) {
#pragma unroll
    for (int i = 0; i < 8; i++)
      gld_lds16(Ag + (long)i * 8 * LDA + kt, As + ldsOffA + i * 512);
#pragma unroll
    for (int i = 0; i < 4; i++)
      gld_lds16(Bg + (long)i * 8 * K + kt, Bs + ldsOffB + i * 512);
    __syncthreads();
#pragma unroll
    for (int ks = 0; ks < 2; ks++) {
      const int kx = ((ks * 4 + q) ^ mx7) * 8;
      half8 a[8], b[4];
#pragma unroll
      for (int mi = 0; mi < 8; mi++)
        a[mi] = *(const half8*)(&As[(wr * 128 + mi * 16 + m16) * BK + kx]);
#pragma unroll
      for (int ni = 0; ni < 4; ni++)
        b[ni] = *(const half8*)(&Bs[(wc * 64 + ni * 16 + m16) * BK + kx]);
      __builtin_amdgcn_s_setprio(1);
#pragma unroll
      for (int mi = 0; mi < 8; mi++)
#pragma unroll
        for (int ni = 0; ni < 4; ni++)
          acc[mi][ni] = __builtin_amdgcn_mfma_f32_16x16x32_f16(
              a[mi], b[ni], acc[mi][ni], 0, 0, 0);
      __builtin_amdgcn_s_setprio(0);
    }
    __syncthreads();
  }

#pragma unroll
  for (int mi = 0; mi < 8; mi++)
#pragma unroll
    for (int r = 0; r < 4; r++) {
      const long rr = rowBase + wr * 128 + mi * 16 + q * 4 + r;
#pragma unroll
      for (int ni = 0; ni < 4; ni++)
        unsafeAtomicAdd(&O[rr * D_MODEL + colBase + wc * 64 + ni * 16 + m16],
                        acc[mi][ni][r]);
    }
}

// ---------------------------------------------------------------------------
// softmax over rows of 4096: fp32 S in, fp16 P out in-place at row start.
// ---------------------------------------------------------------------------
__global__ __launch_bounds__(256) void softmax_kernel(float* __restrict__ S) {
  float* s = S + (long)blockIdx.x * D_FF;
  const int t = threadIdx.x;
  const int lane = t & 63, wave = t >> 6;
  __shared__ float redm[4], redl[4];

  float v[16];
  float mx = -3.4e38f;
#pragma unroll
  for (int seg = 0; seg < 4; seg++) {
    const float4 f = *(const float4*)(s + seg * 1024 + t * 4);
    v[seg * 4 + 0] = f.x; v[seg * 4 + 1] = f.y;
    v[seg * 4 + 2] = f.z; v[seg * 4 + 3] = f.w;
  }
#pragma unroll
  for (int j = 0; j < 16; j++) mx = fmaxf(mx, v[j]);
#pragma unroll
  for (int off = 32; off >= 1; off >>= 1) mx = fmaxf(mx, __shfl_xor(mx, off));
  if (lane == 0) redm[wave] = mx;
  __syncthreads();
  const float m = fmaxf(fmaxf(redm[0], redm[1]), fmaxf(redm[2], redm[3]));

  float sum = 0.f;
#pragma unroll
  for (int j = 0; j < 16; j++) {
    v[j] = __expf(v[j] - m);
    sum += v[j];
  }
#pragma unroll
  for (int off = 32; off >= 1; off >>= 1) sum += __shfl_xor(sum, off);
  if (lane == 0) redl[wave] = sum;
  __syncthreads();
  const float inv = 1.f / (redl[0] + redl[1] + redl[2] + redl[3]);

  _Float16* p = (_Float16*)s;  // all reads of this row completed above
#pragma unroll
  for (int seg = 0; seg < 4; seg++) {
    half4 h;
#pragma unroll
    for (int j = 0; j < 4; j++) h[j] = (_Float16)(v[seg * 4 + j] * inv);
    *(half4*)(p + seg * 1024 + t * 4) = h;
  }
}

// ---------------------------------------------------------------------------
extern "C" void kernel_launch(void* const* d_in, const int* in_sizes, int n_in,
                              void* d_out, int out_size, void* d_ws, size_t ws_size,
                              hipStream_t stream) {
  const float* x = (const float*)d_in[0];  // [16384,1024] fp32
  const float* w = (const float*)d_in[1];  // [4096,1024] fp32
  float* out = (float*)d_out;              // [16384,1024] fp32

  // ws layout: xh 32Mi | (unused 32Mi) | wh 8Mi | (unused 8Mi) | wT 8Mi |
  //            S 64Mi = 152Mi  (offsets kept from prior rounds)
  const size_t NEED = 152ull << 20;
  if (ws_size < NEED) return;

  char* ws = (char*)d_ws;
  _Float16* xh = (_Float16*)(ws);
  _Float16* wh = (_Float16*)(ws + (64ull << 20));
  _Float16* wT = (_Float16*)(ws + (80ull << 20));
  float*    S  = (float*)   (ws + (88ull << 20));

  // gemm2 accumulates via atomics -> zero d_out first (graph-capture safe)
  hipMemsetAsync(d_out, 0, (size_t)M_ROWS * D_MODEL * sizeof(float), stream);

  hipLaunchKernelGGL(rmsnorm_kernel, dim3(MB_X + MB_W), dim3(256), 0,
                     stream, x, xh, w, wh);
  hipLaunchKernelGGL(transpose_kernel, dim3(D_MODEL / 32, D_FF / 32), dim3(256),
                     0, stream, w, wT);

  for (int c = 0; c < M_ROWS / MC; c++) {
    const long ro = (long)c * MC;
    hipLaunchKernelGGL(gemm1_kernel, dim3(D_FF / 256, MC / 128), dim3(256), 0,
                       stream, xh + ro * D_MODEL, wh, S);
    hipLaunchKernelGGL(softmax_kernel, dim3(MC), dim3(256), 0, stream, S);
    hipLaunchKernelGGL(gemm2_kernel, dim3(D_MODEL / 128, MC / 256, 4),
                       dim3(256), 0, stream, (const _Float16*)S, wT,
                       out + ro * D_MODEL);
  }
}

// Round 9
// 548.136 us; speedup vs baseline: 1.1836x; 1.1836x over previous
//
#include <hip/hip_runtime.h>
#include <hip/hip_fp16.h>

// ---------------------------------------------------------------------------
// VQFFN1: out = softmax(rmsnorm(x) @ rmsnorm(w)^T) @ w
//   x: [16384,1024] fp32   w: [4096,1024] fp32   out: [16384,1024] fp32
// fp32 scores; GEMM2 plain fp16 + split-K + f32 HW atomics.
// R2: XOR-swizzled LDS (bank conflicts 3.8e7 -> 0).
// R8: gemm2 BK 64->128 (drain halving = the big gemm2 lever).
// R9/R10/R11 FAILED: fine-phase / 1-block-per-CU schedules lost 2-blocks/CU
//     overlap (m114). R12 NEUTRAL: 32x32x16 inherent 4-way conflict.
// R13 WIN (-80us): dropped xl@wh (single-pass gemm1); 570us, absmax 9.2e-4
//     (P->fp16 quantization dominates output error).
// R14 FAILED: gemm2 BK=64 256x128 split-4: conflicts 0 but drains/FLOP
//     doubled + atomics doubled -> 58->79us. Lever ranking established:
//     drains/FLOP >> atomics > bank conflicts.
// R15: gemm2 = R13 chassis (128x128, BK=128, split-K=2, 64 MFMA/drain)
//     with BK=128 tiles stored as TWO BK=64 HALF-TILES, each in gemm1's
//     measured-0-conflict layout (128B row stride, 3-bit XOR swizzle).
//     Removes the 4 cyc/read tax (~6.8us/dispatch) at identical economics.
// ---------------------------------------------------------------------------

#define D_MODEL 1024
#define D_FF    4096
#define M_ROWS  16384
#define MC      4096

typedef _Float16 half8 __attribute__((ext_vector_type(8)));
typedef _Float16 half4 __attribute__((ext_vector_type(4)));
typedef float    floatx4 __attribute__((ext_vector_type(4)));

// async global->LDS, 16B/lane; LDS dst = wave-uniform base + lane*16 (m97)
__device__ __forceinline__ void gld_lds16(const void* g, void* l) {
  __builtin_amdgcn_global_load_lds(
      (const __attribute__((address_space(1))) void*)g,
      (__attribute__((address_space(3))) void*)l, 16, 0, 0);
}

// ---------------------------------------------------------------------------
// rmsnorm (fp32 in) -> fp16. One wave per row of 1024.
// ---------------------------------------------------------------------------
#define MB_X (M_ROWS / 4)
#define MB_W (D_FF / 4)
__global__ __launch_bounds__(256) void rmsnorm_kernel(
    const float* __restrict__ X, _Float16* __restrict__ XH,
    const float* __restrict__ W, _Float16* __restrict__ WH) {
  const int lane = threadIdx.x & 63;
  const bool isW = blockIdx.x >= MB_X;
  const long row = (long)(isW ? blockIdx.x - MB_X : blockIdx.x) * 4 +
                   (threadIdx.x >> 6);
  const float* x = (isW ? W : X) + row * D_MODEL;
  _Float16* YH = (isW ? WH : XH) + row * D_MODEL;

  float v[16];
  float ss = 0.f;
#pragma unroll
  for (int s = 0; s < 4; s++) {
    const float4 f = *(const float4*)(x + s * 256 + lane * 4);
    v[s * 4 + 0] = f.x; v[s * 4 + 1] = f.y;
    v[s * 4 + 2] = f.z; v[s * 4 + 3] = f.w;
    ss += f.x * f.x + f.y * f.y + f.z * f.z + f.w * f.w;
  }
#pragma unroll
  for (int off = 32; off >= 1; off >>= 1) ss += __shfl_xor(ss, off);
  const float inv = rsqrtf(ss * (1.0f / D_MODEL) + 1e-6f);
#pragma unroll
  for (int s = 0; s < 4; s++) {
    half4 h;
#pragma unroll
    for (int j = 0; j < 4; j++) h[j] = (_Float16)(v[s * 4 + j] * inv);
    *(half4*)(YH + s * 256 + lane * 4) = h;
  }
}

// ---------------------------------------------------------------------------
// transpose w [4096,1024] fp32 -> wT [1024,4096] fp16 (unnormalized, GEMM2 B)
// ---------------------------------------------------------------------------
__global__ __launch_bounds__(256) void transpose_kernel(
    const float* __restrict__ W, _Float16* __restrict__ WT) {
  __shared__ _Float16 tile[32][33];
  const int tx = threadIdx.x & 31;
  const int ty = threadIdx.x >> 5;  // 0..7
  const int d0 = blockIdx.x * 32;
  const int c0 = blockIdx.y * 32;
#pragma unroll
  for (int i = 0; i < 32; i += 8)
    tile[ty + i][tx] = (_Float16)W[(long)(c0 + ty + i) * D_MODEL + d0 + tx];
  __syncthreads();
#pragma unroll
  for (int i = 0; i < 32; i += 8)
    WT[(long)(d0 + ty + i) * D_FF + c0 + tx] = tile[tx][ty + i];
}

// ---------------------------------------------------------------------------
// GEMM K-loops: m97 structure + R2 XOR swizzle (single LDS buffer).
// LDS slot (row, s) holds global data (row, s ^ (row&7)); swizzle applied by
// permuting the *global source* lane address. Fragment reads XOR the k-slot
// with m16&7 -> conflict-free ds_read_b128 (measured 0).
// ---------------------------------------------------------------------------

// GEMM1: S[4096,4096] fp32 = xh @ wh^T over K=1024.  (single-pass, R13)
// 128x256 block tile, 4 waves, wave tile 64x128 (acc[4][8]); per ks:
// 12 LDS reads feed 32 MFMA. LDS 48KB -> 2 blocks/CU (m114 overlap).
__global__ __launch_bounds__(256, 2) void gemm1_kernel(
    const _Float16* __restrict__ XH, const _Float16* __restrict__ WH,
    float* __restrict__ S) {
  constexpr int BK = 64;
  __shared__ _Float16 Ah[128 * BK];  // xh tile (16 KB)
  __shared__ _Float16 Bs[256 * BK];  // wh tile (32 KB)
  const int tid = threadIdx.x;
  const int wave = tid >> 6, lane = tid & 63;
  const long rowBase = (long)blockIdx.y * 128;
  const long colBase = (long)blockIdx.x * 256;
  const int srow = lane >> 3;
  const int scol = ((lane & 7) ^ (lane >> 3)) * 8;  // XOR-swizzled source col
  const _Float16* AgH = XH + (rowBase + wave * 32 + srow) * (long)D_MODEL + scol;
  const _Float16* Bg  = WH + (colBase + wave * 64 + srow) * (long)D_MODEL + scol;
  const int ldsOffA = wave * 2048 + lane * 8;  // 32 rows/wave
  const int ldsOffB = wave * 4096 + lane * 8;  // 64 rows/wave
  const int wr = wave >> 1, wc = wave & 1;
  const int m16 = lane & 15, q = lane >> 4;
  const int mx7 = m16 & 7;

  floatx4 acc[4][8] = {};

  for (int kt = 0; kt < D_MODEL; kt += BK) {
#pragma unroll
    for (int i = 0; i < 4; i++)
      gld_lds16(AgH + i * 8 * D_MODEL + kt, Ah + ldsOffA + i * 512);
#pragma unroll
    for (int i = 0; i < 8; i++)
      gld_lds16(Bg + i * 8 * D_MODEL + kt, Bs + ldsOffB + i * 512);
    __syncthreads();
#pragma unroll
    for (int ks = 0; ks < 2; ks++) {
      const int kx = ((ks * 4 + q) ^ mx7) * 8;
      half8 b[8], a[4];
#pragma unroll
      for (int ni = 0; ni < 8; ni++)
        b[ni] = *(const half8*)(&Bs[(wc * 128 + ni * 16 + m16) * BK + kx]);
#pragma unroll
      for (int mi = 0; mi < 4; mi++)
        a[mi] = *(const half8*)(&Ah[(wr * 64 + mi * 16 + m16) * BK + kx]);
      __builtin_amdgcn_s_setprio(1);
#pragma unroll
      for (int mi = 0; mi < 4; mi++)
#pragma unroll
        for (int ni = 0; ni < 8; ni++)
          acc[mi][ni] = __builtin_amdgcn_mfma_f32_16x16x32_f16(
              a[mi], b[ni], acc[mi][ni], 0, 0, 0);
      __builtin_amdgcn_s_setprio(0);
    }
    __syncthreads();
  }

  // C/D frag: col = lane&15, row = quad*4 + reg  [m89/m91 verified]
#pragma unroll
  for (int mi = 0; mi < 4; mi++)
#pragma unroll
    for (int r = 0; r < 4; r++) {
      const long rr = rowBase + wr * 64 + mi * 16 + q * 4 + r;
#pragma unroll
      for (int ni = 0; ni < 8; ni++)
        S[rr * D_FF + colBase + wc * 128 + ni * 16 + m16] = acc[mi][ni][r];
    }
}

// ---------------------------------------------------------------------------
// GEMM2: O[4096,1024] fp32 += P[4096, lda 8192] @ WT[1024,4096]^T  (R15)
// 128x128 block tile, BK=128 as TWO BK=64 half-tiles (each the gemm1
// 0-conflict layout), split-K=2, 64 MFMA/wave per drain (R13 economics).
// LDS 64KB -> 2 blocks/CU. 16 staging instr/iter (4 per operand-half).
// HW f32 atomics into pre-zeroed O.
// ---------------------------------------------------------------------------
__global__ __launch_bounds__(256, 2) void gemm2_kernel(
    const _Float16* __restrict__ P, const _Float16* __restrict__ WT,
    float* __restrict__ O) {
  constexpr int K = D_FF, LDA = 2 * D_FF, KSPLIT = 2048;
  __shared__ _Float16 As[2][128 * 64];  // P tile halves  (2 x 16 KB)
  __shared__ _Float16 Bs[2][128 * 64];  // wT tile halves (2 x 16 KB)
  const int tid = threadIdx.x;
  const int wave = tid >> 6, lane = tid & 63;

  // XCD-chunked bijective swizzle (nwg = 8*32*2 = 512, %8 == 0)
  const int bid = ((blockIdx.z * 32 + blockIdx.y) << 3) | blockIdx.x;
  const int swz = ((bid & 7) << 6) | (bid >> 3);
  const int bx = swz & 7;          // col-block   0..7
  const int by = (swz >> 3) & 31;  // row-block   0..31
  const int bz = swz >> 8;         // K-split     0..1

  const long rowBase = (long)by * 128;
  const long colBase = (long)bx * 128;
  const int k0 = bz * KSPLIT;

  // gemm1-style staging: instr = 8 rows x 64 slots; srow = lane>>3,
  // swizzled source col = ((lane&7) ^ (lane>>3)) * 8  (within a half)
  const int srow = lane >> 3;
  const int scol = ((lane & 7) ^ (lane >> 3)) * 8;
  const _Float16* Ag = P + (rowBase + wave * 32 + srow) * (long)LDA + scol;
  const _Float16* Bg = WT + (colBase + wave * 32 + srow) * (long)K + scol;
  const int ldsOff = wave * 2048 + lane * 8;  // 32 rows/wave per half
  const int wr = wave >> 1, wc = wave & 1;
  const int m16 = lane & 15, q = lane >> 4;
  const int mx7 = m16 & 7;

  floatx4 acc[4][4] = {};

  for (int kt = k0; kt < k0 + KSPLIT; kt += 128) {
#pragma unroll
    for (int h = 0; h < 2; h++) {
      const int kh = kt + h * 64;
#pragma unroll
      for (int i = 0; i < 4; i++) {
        gld_lds16(Ag + (long)i * 8 * LDA + kh, &As[h][ldsOff + i * 512]);
        gld_lds16(Bg + (long)i * 8 * K + kh, &Bs[h][ldsOff + i * 512]);
      }
    }
    __syncthreads();
#pragma unroll
    for (int h = 0; h < 2; h++)
#pragma unroll
      for (int ks = 0; ks < 2; ks++) {
        const int kx = ((ks * 4 + q) ^ mx7) * 8;
        half8 a[4], b[4];
#pragma unroll
        for (int mi = 0; mi < 4; mi++)
          a[mi] = *(const half8*)(&As[h][(wr * 64 + mi * 16 + m16) * 64 + kx]);
#pragma unroll
        for (int ni = 0; ni < 4; ni++)
          b[ni] = *(const half8*)(&Bs[h][(wc * 64 + ni * 16 + m16) * 64 + kx]);
        __builtin_amdgcn_s_setprio(1);
#pragma unroll
        for (int mi = 0; mi < 4; mi++)
#pragma unroll
          for (int ni = 0; ni < 4; ni++)
            acc[mi][ni] = __builtin_amdgcn_mfma_f32_16x16x32_f16(
                a[mi], b[ni], acc[mi][ni], 0, 0, 0);
        __builtin_amdgcn_s_setprio(0);
      }
    __syncthreads();
  }

#pragma unroll
  for (int mi = 0; mi < 4; mi++)
#pragma unroll
    for (int r = 0; r < 4; r++) {
      const long rr = rowBase + wr * 64 + mi * 16 + q * 4 + r;
#pragma unroll
      for (int ni = 0; ni < 4; ni++)
        unsafeAtomicAdd(&O[rr * D_MODEL + colBase + wc * 64 + ni * 16 + m16],
                        acc[mi][ni][r]);
    }
}

// ---------------------------------------------------------------------------
// softmax over rows of 4096: fp32 S in, fp16 P out in-place at row start.
// ---------------------------------------------------------------------------
__global__ __launch_bounds__(256) void softmax_kernel(float* __restrict__ S) {
  float* s = S + (long)blockIdx.x * D_FF;
  const int t = threadIdx.x;
  const int lane = t & 63, wave = t >> 6;
  __shared__ float redm[4], redl[4];

  float v[16];
  float mx = -3.4e38f;
#pragma unroll
  for (int seg = 0; seg < 4; seg++) {
    const float4 f = *(const float4*)(s + seg * 1024 + t * 4);
    v[seg * 4 + 0] = f.x; v[seg * 4 + 1] = f.y;
    v[seg * 4 + 2] = f.z; v[seg * 4 + 3] = f.w;
  }
#pragma unroll
  for (int j = 0; j < 16; j++) mx = fmaxf(mx, v[j]);
#pragma unroll
  for (int off = 32; off >= 1; off >>= 1) mx = fmaxf(mx, __shfl_xor(mx, off));
  if (lane == 0) redm[wave] = mx;
  __syncthreads();
  const float m = fmaxf(fmaxf(redm[0], redm[1]), fmaxf(redm[2], redm[3]));

  float sum = 0.f;
#pragma unroll
  for (int j = 0; j < 16; j++) {
    v[j] = __expf(v[j] - m);
    sum += v[j];
  }
#pragma unroll
  for (int off = 32; off >= 1; off >>= 1) sum += __shfl_xor(sum, off);
  if (lane == 0) redl[wave] = sum;
  __syncthreads();
  const float inv = 1.f / (redl[0] + redl[1] + redl[2] + redl[3]);

  _Float16* p = (_Float16*)s;  // all reads of this row completed above
#pragma unroll
  for (int seg = 0; seg < 4; seg++) {
    half4 h;
#pragma unroll
    for (int j = 0; j < 4; j++) h[j] = (_Float16)(v[seg * 4 + j] * inv);
    *(half4*)(p + seg * 1024 + t * 4) = h;
  }
}

// ---------------------------------------------------------------------------
extern "C" void kernel_launch(void* const* d_in, const int* in_sizes, int n_in,
                              void* d_out, int out_size, void* d_ws, size_t ws_size,
                              hipStream_t stream) {
  const float* x = (const float*)d_in[0];  // [16384,1024] fp32
  const float* w = (const float*)d_in[1];  // [4096,1024] fp32
  float* out = (float*)d_out;              // [16384,1024] fp32

  // ws layout: xh 32Mi | (unused 32Mi) | wh 8Mi | (unused 8Mi) | wT 8Mi |
  //            S 64Mi = 152Mi  (offsets kept from prior rounds)
  const size_t NEED = 152ull << 20;
  if (ws_size < NEED) return;

  char* ws = (char*)d_ws;
  _Float16* xh = (_Float16*)(ws);
  _Float16* wh = (_Float16*)(ws + (64ull << 20));
  _Float16* wT = (_Float16*)(ws + (80ull << 20));
  float*    S  = (float*)   (ws + (88ull << 20));

  // gemm2 accumulates via atomics -> zero d_out first (graph-capture safe)
  hipMemsetAsync(d_out, 0, (size_t)M_ROWS * D_MODEL * sizeof(float), stream);

  hipLaunchKernelGGL(rmsnorm_kernel, dim3(MB_X + MB_W), dim3(256), 0,
                     stream, x, xh, w, wh);
  hipLaunchKernelGGL(transpose_kernel, dim3(D_MODEL / 32, D_FF / 32), dim3(256),
                     0, stream, w, wT);

  for (int c = 0; c < M_ROWS / MC; c++) {
    const long ro = (long)c * MC;
    hipLaunchKernelGGL(gemm1_kernel, dim3(D_FF / 256, MC / 128), dim3(256), 0,
                       stream, xh + ro * D_MODEL, wh, S);
    hipLaunchKernelGGL(softmax_kernel, dim3(MC), dim3(256), 0, stream, S);
    hipLaunchKernelGGL(gemm2_kernel, dim3(D_MODEL / 128, MC / 128, 2),
                       dim3(256), 0, stream, (const _Float16*)S, wT,
                       out + ro * D_MODEL);
  }
}